// Round 1
// baseline (803.645 us; speedup 1.0000x reference)
//
#include <hip/hip_runtime.h>
#include <hip/hip_bf16.h>

#define N_TOK 16384
#define D_IN 1024
#define D_HID 256
#define D_OUT 1024
#define N_EXP 8

typedef float f32x4 __attribute__((ext_vector_type(4)));
typedef short s16x8 __attribute__((ext_vector_type(8)));
typedef short s16x4 __attribute__((ext_vector_type(4)));

__device__ __forceinline__ short f2bf(float f) {
    unsigned u = __builtin_bit_cast(unsigned, f);
    u += 0x7FFF + ((u >> 16) & 1);   // round-to-nearest-even
    return (short)(u >> 16);
}

// ---------------- zero counts ----------------
__global__ void zero_kernel(int* cnt) {
    if (threadIdx.x < N_EXP) cnt[threadIdx.x] = 0;
}

// ---------------- transpose + convert: src f32 [E][R][C] -> dst bf16 [E][C][R] ----------------
__global__ __launch_bounds__(256) void transpose_cvt_kernel(
    const float* __restrict__ src, short* __restrict__ dst, int R, int C)
{
    __shared__ short tile[32][33];
    int e = blockIdx.z;
    int r0 = blockIdx.y * 32, c0 = blockIdx.x * 32;
    const float* s = src + (size_t)e * R * C;
    short* d = dst + (size_t)e * R * C;
    int tr = threadIdx.x >> 5, tc = threadIdx.x & 31;
    #pragma unroll
    for (int i = 0; i < 4; ++i) {
        int r = tr + i * 8;
        tile[r][tc] = f2bf(s[(size_t)(r0 + r) * C + c0 + tc]);
    }
    __syncthreads();
    #pragma unroll
    for (int i = 0; i < 4; ++i) {
        int rr = tr + i * 8;       // dst-row (src col) within tile
        d[(size_t)(c0 + rr) * R + r0 + tc] = tile[tc][rr];
    }
}

// ---------------- gating: logits (fp32 exact), top-2, softmax, dispatch ----------------
__global__ __launch_bounds__(256) void gate_kernel(
    const float* __restrict__ x, const float* __restrict__ Wg,
    const float* __restrict__ bg, float* __restrict__ gate_out,
    int* __restrict__ cnt, int* __restrict__ lists,
    int* __restrict__ meta_e, float* __restrict__ meta_w)
{
    __shared__ float wgs[D_IN * N_EXP];
    int tid = threadIdx.x;
    #pragma unroll
    for (int i = 0; i < 8; ++i) {
        int idx = i * 1024 + tid * 4;
        *(float4*)&wgs[idx] = *(const float4*)&Wg[idx];
    }
    __syncthreads();

    int lane = tid & 63;
    int t = blockIdx.x * 4 + (tid >> 6);
    const float* xr = x + (size_t)t * D_IN;
    float acc[8] = {0.f, 0.f, 0.f, 0.f, 0.f, 0.f, 0.f, 0.f};
    for (int it = 0; it < 16; ++it) {
        int d = it * 64 + lane;
        float xv = xr[d];
        const float* w = &wgs[d * 8];
        #pragma unroll
        for (int e = 0; e < 8; ++e) acc[e] += xv * w[e];
    }
    #pragma unroll
    for (int e = 0; e < 8; ++e) {
        #pragma unroll
        for (int off = 32; off >= 1; off >>= 1)
            acc[e] += __shfl_xor(acc[e], off);
    }
    if (lane == 0) {
        float lg[8];
        #pragma unroll
        for (int e = 0; e < 8; ++e) {
            lg[e] = acc[e] + bg[e];
            gate_out[(size_t)t * 8 + e] = lg[e];
        }
        int i0 = 0;
        #pragma unroll
        for (int e = 1; e < 8; ++e) if (lg[e] > lg[i0]) i0 = e;  // ties -> lowest idx
        int i1 = -1;
        #pragma unroll
        for (int e = 0; e < 8; ++e)
            if (e != i0 && (i1 < 0 || lg[e] > lg[i1])) i1 = e;
        float ex = expf(lg[i1] - lg[i0]);
        float inv = 1.f / (1.f + ex);
        float w0 = inv, w1 = ex * inv;
        meta_e[2 * t] = i0; meta_e[2 * t + 1] = i1;
        meta_w[2 * t] = w0; meta_w[2 * t + 1] = w1;
        int p0 = atomicAdd(&cnt[i0], 1);
        lists[i0 * N_TOK + p0] = t * 2;
        int p1 = atomicAdd(&cnt[i1], 1);
        lists[i1 * N_TOK + p1] = t * 2 + 1;
    }
}

// ---------------- out pre-init with combined bias: out[t] = w0*b2[e0] + w1*b2[e1] ----------------
__global__ __launch_bounds__(256) void init_out_kernel(
    const int* __restrict__ meta_e, const float* __restrict__ meta_w,
    const float* __restrict__ b2, float* __restrict__ out)
{
    int t = blockIdx.x;
    int e0 = meta_e[2 * t], e1 = meta_e[2 * t + 1];
    float w0 = meta_w[2 * t], w1 = meta_w[2 * t + 1];
    int c = threadIdx.x * 4;
    float4 a = *(const float4*)&b2[(size_t)e0 * D_OUT + c];
    float4 b = *(const float4*)&b2[(size_t)e1 * D_OUT + c];
    float4 r;
    r.x = w0 * a.x + w1 * b.x;
    r.y = w0 * a.y + w1 * b.y;
    r.z = w0 * a.z + w1 * b.z;
    r.w = w0 * a.w + w1 * b.w;
    *(float4*)&out[(size_t)t * D_OUT + c] = r;
}

// ---------------- expert MLP: 16-token tile, bf16 MFMA, atomic scatter-add ----------------
#define XS_LD 1032   // 1024 + 8 bf16 pad (16B-aligned rows, 2-way-free banks)
#define HS_LD 264    // 256 + 8 bf16 pad

__global__ __launch_bounds__(256) void expert_kernel(
    const float* __restrict__ x,
    const short* __restrict__ W1T, const short* __restrict__ W2T,
    const float* __restrict__ b1,
    const int* __restrict__ cnt, const int* __restrict__ lists,
    const float* __restrict__ meta_w,
    float* __restrict__ out)
{
    int e = blockIdx.y;
    int me = cnt[e];
    int base = blockIdx.x * 16;
    if (base >= me) return;

    __shared__ short xs[16 * XS_LD];
    __shared__ short hs[16 * HS_LD];
    __shared__ int toks[16];
    __shared__ float wts[16];

    int tid = threadIdx.x;
    if (tid < 16) {
        int gi = base + tid;
        if (gi < me) {
            int enc = lists[e * N_TOK + gi];
            toks[tid] = enc >> 1;
            wts[tid] = meta_w[enc];
        } else {
            toks[tid] = 0;
            wts[tid] = 0.f;
        }
    }
    __syncthreads();

    // stage X tile (16 x 1024) as bf16 in LDS, coalesced float4 loads
    for (int row = 0; row < 16; ++row) {
        const float4 v = *(const float4*)&x[(size_t)toks[row] * D_IN + tid * 4];
        s16x4 pk; pk[0] = f2bf(v.x); pk[1] = f2bf(v.y); pk[2] = f2bf(v.z); pk[3] = f2bf(v.w);
        *(s16x4*)&xs[row * XS_LD + tid * 4] = pk;
    }
    __syncthreads();

    int lane = tid & 63;
    int wv = tid >> 6;               // wave 0..3
    int m = lane & 15, q = lane >> 4;

    // ---- GEMM1: H[16x256] = relu(X @ W1 + b1); wave owns 64 hidden cols ----
    f32x4 acc1[4] = {{0.f,0.f,0.f,0.f},{0.f,0.f,0.f,0.f},{0.f,0.f,0.f,0.f},{0.f,0.f,0.f,0.f}};
    const short* w1e = W1T + (size_t)e * D_HID * D_IN;   // [256][1024]
    for (int kk = 0; kk < 32; ++kk) {
        s16x8 a = *(const s16x8*)&xs[m * XS_LD + kk * 32 + q * 8];
        #pragma unroll
        for (int nt = 0; nt < 4; ++nt) {
            int n = wv * 64 + nt * 16 + m;
            s16x8 b = *(const s16x8*)&w1e[(size_t)n * D_IN + kk * 32 + q * 8];
            acc1[nt] = __builtin_amdgcn_mfma_f32_16x16x32_bf16(a, b, acc1[nt], 0, 0, 0);
        }
    }
    const float* b1e = b1 + (size_t)e * D_HID;
    #pragma unroll
    for (int nt = 0; nt < 4; ++nt) {
        int j = wv * 64 + nt * 16 + m;        // C/D: col = lane&15
        float bias = b1e[j];
        #pragma unroll
        for (int r = 0; r < 4; ++r) {
            int row = q * 4 + r;              // C/D: row = (lane>>4)*4 + reg
            float h = acc1[nt][r] + bias;
            h = h > 0.f ? h : 0.f;
            hs[row * HS_LD + j] = f2bf(h);
        }
    }
    __syncthreads();

    // ---- GEMM2: Y[16x1024] = H @ W2; wave owns 256 out cols ----
    f32x4 acc2[16];
    #pragma unroll
    for (int nt = 0; nt < 16; ++nt) acc2[nt] = (f32x4){0.f, 0.f, 0.f, 0.f};
    const short* w2e = W2T + (size_t)e * D_OUT * D_HID;  // [1024][256]
    for (int kk = 0; kk < 8; ++kk) {
        s16x8 a = *(const s16x8*)&hs[m * HS_LD + kk * 32 + q * 8];
        #pragma unroll
        for (int nt = 0; nt < 16; ++nt) {
            int n = wv * 256 + nt * 16 + m;
            s16x8 b = *(const s16x8*)&w2e[(size_t)n * D_HID + kk * 32 + q * 8];
            acc2[nt] = __builtin_amdgcn_mfma_f32_16x16x32_bf16(a, b, acc2[nt], 0, 0, 0);
        }
    }

    // ---- epilogue: out[tok] += w * Y  (bias already pre-initialized) ----
    float wr[4]; int tk[4]; int rv[4];
    #pragma unroll
    for (int r = 0; r < 4; ++r) {
        int row = q * 4 + r;
        tk[r] = toks[row]; wr[r] = wts[row]; rv[r] = (base + row) < me;
    }
    #pragma unroll
    for (int nt = 0; nt < 16; ++nt) {
        int col = wv * 256 + nt * 16 + m;
        #pragma unroll
        for (int r = 0; r < 4; ++r) {
            if (rv[r])
                unsafeAtomicAdd(&out[(size_t)tk[r] * D_OUT + col], wr[r] * acc2[nt][r]);
        }
    }
}

extern "C" void kernel_launch(void* const* d_in, const int* in_sizes, int n_in,
                              void* d_out, int out_size, void* d_ws, size_t ws_size,
                              hipStream_t stream) {
    const float* x  = (const float*)d_in[0];
    const float* Wg = (const float*)d_in[1];
    const float* bg = (const float*)d_in[2];
    const float* W1 = (const float*)d_in[3];
    const float* b1 = (const float*)d_in[4];
    const float* W2 = (const float*)d_in[5];
    const float* b2 = (const float*)d_in[6];

    float* out = (float*)d_out;                         // [16384,1024]
    float* gate_out = out + (size_t)N_TOK * D_OUT;      // [16384,8]

    // workspace layout (~8.8 MB)
    short* W1T   = (short*)d_ws;                        // [8][256][1024] bf16
    short* W2T   = W1T + (size_t)N_EXP * D_HID * D_IN;  // [8][1024][256] bf16
    int*   cnt   = (int*)(W2T + (size_t)N_EXP * D_OUT * D_HID);
    int*   lists = cnt + N_EXP;                         // [8][16384]
    int*   meta_e = lists + N_EXP * N_TOK;              // [16384][2]
    float* meta_w = (float*)(meta_e + 2 * N_TOK);       // [16384][2]

    zero_kernel<<<1, 64, 0, stream>>>(cnt);
    transpose_cvt_kernel<<<dim3(D_HID / 32, D_IN / 32, N_EXP), 256, 0, stream>>>(W1, W1T, D_IN, D_HID);
    transpose_cvt_kernel<<<dim3(D_OUT / 32, D_HID / 32, N_EXP), 256, 0, stream>>>(W2, W2T, D_HID, D_OUT);
    gate_kernel<<<N_TOK / 4, 256, 0, stream>>>(x, Wg, bg, gate_out, cnt, lists, meta_e, meta_w);
    init_out_kernel<<<N_TOK, 256, 0, stream>>>(meta_e, meta_w, b2, out);
    expert_kernel<<<dim3(N_TOK / 16, N_EXP), 256, 0, stream>>>(x, W1T, W2T, b1, cnt, lists, meta_w, out);
}

// Round 2
// 462.213 us; speedup vs baseline: 1.7387x; 1.7387x over previous
//
#include <hip/hip_runtime.h>
#include <hip/hip_bf16.h>

#define N_TOK 16384
#define D_IN 1024
#define D_HID 256
#define D_OUT 1024
#define N_EXP 8
#define CNT_STRIDE 16   // pad expert counters to separate 64B cache lines

typedef float f32x4 __attribute__((ext_vector_type(4)));
typedef short s16x8 __attribute__((ext_vector_type(8)));
typedef short s16x4 __attribute__((ext_vector_type(4)));

__device__ __forceinline__ short f2bf(float f) {
    unsigned u = __builtin_bit_cast(unsigned, f);
    u += 0x7FFF + ((u >> 16) & 1);   // round-to-nearest-even
    return (short)(u >> 16);
}

// ---------------- zero counts ----------------
__global__ void zero_kernel(int* cnt) {
    if (threadIdx.x < N_EXP * CNT_STRIDE) cnt[threadIdx.x] = 0;
}

// ---------------- transpose + convert: src f32 [E][R][C] -> dst bf16 [E][C][R] ----------------
__global__ __launch_bounds__(256) void transpose_cvt_kernel(
    const float* __restrict__ src, short* __restrict__ dst, int R, int C)
{
    __shared__ short tile[32][33];
    int e = blockIdx.z;
    int r0 = blockIdx.y * 32, c0 = blockIdx.x * 32;
    const float* s = src + (size_t)e * R * C;
    short* d = dst + (size_t)e * R * C;
    int tr = threadIdx.x >> 5, tc = threadIdx.x & 31;
    #pragma unroll
    for (int i = 0; i < 4; ++i) {
        int r = tr + i * 8;
        tile[r][tc] = f2bf(s[(size_t)(r0 + r) * C + c0 + tc]);
    }
    __syncthreads();
    #pragma unroll
    for (int i = 0; i < 4; ++i) {
        int rr = tr + i * 8;       // dst-row (src col) within tile
        d[(size_t)(c0 + rr) * R + r0 + tc] = tile[tc][rr];
    }
}

// ---------------- gating: logits (fp32 exact), top-2, softmax, hierarchical dispatch ----------------
// 512 blocks x 32 tokens. Wg staged in LDS with 12-float row stride (48B):
// lane-stride 12 banks, b128 reads cover all 32 banks -> conflict-free optimum.
#define G_TOK 32                 // tokens per block (4 waves x 8 tokens)
__global__ __launch_bounds__(256) void gate_kernel(
    const float* __restrict__ x, const float* __restrict__ Wg,
    const float* __restrict__ bg, float* __restrict__ gate_out,
    int* __restrict__ cnt, int* __restrict__ lists,
    int* __restrict__ meta_e, float* __restrict__ meta_w)
{
    __shared__ float wgs[D_IN * 12];
    __shared__ int lcnt[N_EXP];
    __shared__ int sbase[N_EXP];
    __shared__ int ent_e[2 * G_TOK];
    __shared__ int ent_r[2 * G_TOK];

    int tid = threadIdx.x;
    // stage Wg [1024][8] -> wgs[d*12 + e], float4 moves (j in {0,4} keeps 16B align)
    #pragma unroll
    for (int i = 0; i < 8; ++i) {
        int flat = i * 256 + tid;          // float4 index 0..2047
        int d = flat >> 1, j = (flat & 1) * 4;
        float4 v = *(const float4*)&Wg[d * 8 + j];
        *(float4*)&wgs[d * 12 + j] = v;
    }
    if (tid < N_EXP) lcnt[tid] = 0;
    __syncthreads();

    int lane = tid & 63, wv = tid >> 6;
    int tbase = blockIdx.x * G_TOK;

    for (int i = 0; i < G_TOK / 4; ++i) {
        int lt = wv * (G_TOK / 4) + i;
        int t = tbase + lt;
        const float* xr = x + (size_t)t * D_IN;
        float acc[8] = {0.f, 0.f, 0.f, 0.f, 0.f, 0.f, 0.f, 0.f};
        #pragma unroll
        for (int it = 0; it < 16; ++it) {
            int d = it * 64 + lane;
            float xv = xr[d];
            float4 wa = *(const float4*)&wgs[d * 12 + 0];
            float4 wb = *(const float4*)&wgs[d * 12 + 4];
            acc[0] += xv * wa.x; acc[1] += xv * wa.y;
            acc[2] += xv * wa.z; acc[3] += xv * wa.w;
            acc[4] += xv * wb.x; acc[5] += xv * wb.y;
            acc[6] += xv * wb.z; acc[7] += xv * wb.w;
        }
        #pragma unroll
        for (int e = 0; e < 8; ++e) {
            #pragma unroll
            for (int off = 32; off >= 1; off >>= 1)
                acc[e] += __shfl_xor(acc[e], off);
        }
        if (lane == 0) {
            float lg[8];
            #pragma unroll
            for (int e = 0; e < 8; ++e) {
                lg[e] = acc[e] + bg[e];
                gate_out[(size_t)t * 8 + e] = lg[e];
            }
            int i0 = 0;
            #pragma unroll
            for (int e = 1; e < 8; ++e) if (lg[e] > lg[i0]) i0 = e;   // ties -> lowest idx
            int i1 = -1;
            #pragma unroll
            for (int e = 0; e < 8; ++e)
                if (e != i0 && (i1 < 0 || lg[e] > lg[i1])) i1 = e;
            float ex = expf(lg[i1] - lg[i0]);
            float inv = 1.f / (1.f + ex);
            meta_e[2 * t] = i0; meta_e[2 * t + 1] = i1;
            meta_w[2 * t] = inv; meta_w[2 * t + 1] = ex * inv;
            int r0 = atomicAdd(&lcnt[i0], 1);
            int r1 = atomicAdd(&lcnt[i1], 1);
            ent_e[2 * lt] = i0;     ent_r[2 * lt] = r0;
            ent_e[2 * lt + 1] = i1; ent_r[2 * lt + 1] = r1;
        }
    }
    __syncthreads();
    if (tid < N_EXP) sbase[tid] = atomicAdd(&cnt[tid * CNT_STRIDE], lcnt[tid]);
    __syncthreads();
    if (tid < 2 * G_TOK) {
        int e = ent_e[tid];
        lists[e * N_TOK + sbase[e] + ent_r[tid]] = tbase * 2 + tid;  // code = t*2 + slot
    }
}

// ---------------- out pre-init with combined bias: out[t] = w0*b2[e0] + w1*b2[e1] ----------------
__global__ __launch_bounds__(256) void init_out_kernel(
    const int* __restrict__ meta_e, const float* __restrict__ meta_w,
    const float* __restrict__ b2, float* __restrict__ out)
{
    int t = blockIdx.x;
    int e0 = meta_e[2 * t], e1 = meta_e[2 * t + 1];
    float w0 = meta_w[2 * t], w1 = meta_w[2 * t + 1];
    int c = threadIdx.x * 4;
    float4 a = *(const float4*)&b2[(size_t)e0 * D_OUT + c];
    float4 b = *(const float4*)&b2[(size_t)e1 * D_OUT + c];
    float4 r;
    r.x = w0 * a.x + w1 * b.x;
    r.y = w0 * a.y + w1 * b.y;
    r.z = w0 * a.z + w1 * b.z;
    r.w = w0 * a.w + w1 * b.w;
    *(float4*)&out[(size_t)t * D_OUT + c] = r;
}

// ---------------- expert MLP: 16-token tile, bf16 MFMA, atomic scatter-add ----------------
#define XS_LD 1032   // 1024 + 8 bf16 pad (16B-aligned rows, 2-way-free banks)
#define HS_LD 264    // 256 + 8 bf16 pad

__global__ __launch_bounds__(256) void expert_kernel(
    const float* __restrict__ x,
    const short* __restrict__ W1T, const short* __restrict__ W2T,
    const float* __restrict__ b1,
    const int* __restrict__ cnt, const int* __restrict__ lists,
    const float* __restrict__ meta_w,
    float* __restrict__ out)
{
    int e = blockIdx.y;
    int me = cnt[e * CNT_STRIDE];
    int base = blockIdx.x * 16;
    if (base >= me) return;

    __shared__ short xs[16 * XS_LD];
    __shared__ short hs[16 * HS_LD];
    __shared__ int toks[16];
    __shared__ float wts[16];

    int tid = threadIdx.x;
    if (tid < 16) {
        int gi = base + tid;
        if (gi < me) {
            int enc = lists[e * N_TOK + gi];
            toks[tid] = enc >> 1;
            wts[tid] = meta_w[enc];
        } else {
            toks[tid] = 0;
            wts[tid] = 0.f;
        }
    }
    __syncthreads();

    // stage X tile (16 x 1024) as bf16 in LDS, coalesced float4 loads
    for (int row = 0; row < 16; ++row) {
        const float4 v = *(const float4*)&x[(size_t)toks[row] * D_IN + tid * 4];
        s16x4 pk; pk[0] = f2bf(v.x); pk[1] = f2bf(v.y); pk[2] = f2bf(v.z); pk[3] = f2bf(v.w);
        *(s16x4*)&xs[row * XS_LD + tid * 4] = pk;
    }
    __syncthreads();

    int lane = tid & 63;
    int wv = tid >> 6;               // wave 0..3
    int m = lane & 15, q = lane >> 4;

    // ---- GEMM1: H[16x256] = relu(X @ W1 + b1); wave owns 64 hidden cols ----
    f32x4 acc1[4] = {{0.f,0.f,0.f,0.f},{0.f,0.f,0.f,0.f},{0.f,0.f,0.f,0.f},{0.f,0.f,0.f,0.f}};
    const short* w1e = W1T + (size_t)e * D_HID * D_IN;   // [256][1024]
    for (int kk = 0; kk < 32; ++kk) {
        s16x8 a = *(const s16x8*)&xs[m * XS_LD + kk * 32 + q * 8];
        #pragma unroll
        for (int nt = 0; nt < 4; ++nt) {
            int n = wv * 64 + nt * 16 + m;
            s16x8 b = *(const s16x8*)&w1e[(size_t)n * D_IN + kk * 32 + q * 8];
            acc1[nt] = __builtin_amdgcn_mfma_f32_16x16x32_bf16(a, b, acc1[nt], 0, 0, 0);
        }
    }
    const float* b1e = b1 + (size_t)e * D_HID;
    #pragma unroll
    for (int nt = 0; nt < 4; ++nt) {
        int j = wv * 64 + nt * 16 + m;        // C/D: col = lane&15
        float bias = b1e[j];
        #pragma unroll
        for (int r = 0; r < 4; ++r) {
            int row = q * 4 + r;              // C/D: row = (lane>>4)*4 + reg
            float h = acc1[nt][r] + bias;
            h = h > 0.f ? h : 0.f;
            hs[row * HS_LD + j] = f2bf(h);
        }
    }
    __syncthreads();

    // ---- GEMM2: Y[16x1024] = H @ W2; wave owns 256 out cols ----
    f32x4 acc2[16];
    #pragma unroll
    for (int nt = 0; nt < 16; ++nt) acc2[nt] = (f32x4){0.f, 0.f, 0.f, 0.f};
    const short* w2e = W2T + (size_t)e * D_OUT * D_HID;  // [1024][256]
    for (int kk = 0; kk < 8; ++kk) {
        s16x8 a = *(const s16x8*)&hs[m * HS_LD + kk * 32 + q * 8];
        #pragma unroll
        for (int nt = 0; nt < 16; ++nt) {
            int n = wv * 256 + nt * 16 + m;
            s16x8 b = *(const s16x8*)&w2e[(size_t)n * D_HID + kk * 32 + q * 8];
            acc2[nt] = __builtin_amdgcn_mfma_f32_16x16x32_bf16(a, b, acc2[nt], 0, 0, 0);
        }
    }

    // ---- epilogue: out[tok] += w * Y  (bias already pre-initialized) ----
    float wr[4]; int tk[4]; int rv[4];
    #pragma unroll
    for (int r = 0; r < 4; ++r) {
        int row = q * 4 + r;
        tk[r] = toks[row]; wr[r] = wts[row]; rv[r] = (base + row) < me;
    }
    #pragma unroll
    for (int nt = 0; nt < 16; ++nt) {
        int col = wv * 256 + nt * 16 + m;
        #pragma unroll
        for (int r = 0; r < 4; ++r) {
            if (rv[r])
                unsafeAtomicAdd(&out[(size_t)tk[r] * D_OUT + col], wr[r] * acc2[nt][r]);
        }
    }
}

extern "C" void kernel_launch(void* const* d_in, const int* in_sizes, int n_in,
                              void* d_out, int out_size, void* d_ws, size_t ws_size,
                              hipStream_t stream) {
    const float* x  = (const float*)d_in[0];
    const float* Wg = (const float*)d_in[1];
    const float* bg = (const float*)d_in[2];
    const float* W1 = (const float*)d_in[3];
    const float* b1 = (const float*)d_in[4];
    const float* W2 = (const float*)d_in[5];
    const float* b2 = (const float*)d_in[6];

    float* out = (float*)d_out;                         // [16384,1024]
    float* gate_out = out + (size_t)N_TOK * D_OUT;      // [16384,8]

    // workspace layout (~8.8 MB)
    short* W1T   = (short*)d_ws;                        // [8][256][1024] bf16
    short* W2T   = W1T + (size_t)N_EXP * D_HID * D_IN;  // [8][1024][256] bf16
    int*   cnt   = (int*)(W2T + (size_t)N_EXP * D_OUT * D_HID);  // [8*16] padded
    int*   lists = cnt + N_EXP * CNT_STRIDE;            // [8][16384]
    int*   meta_e = lists + N_EXP * N_TOK;              // [16384][2]
    float* meta_w = (float*)(meta_e + 2 * N_TOK);       // [16384][2]

    zero_kernel<<<1, 128, 0, stream>>>(cnt);
    transpose_cvt_kernel<<<dim3(D_HID / 32, D_IN / 32, N_EXP), 256, 0, stream>>>(W1, W1T, D_IN, D_HID);
    transpose_cvt_kernel<<<dim3(D_OUT / 32, D_HID / 32, N_EXP), 256, 0, stream>>>(W2, W2T, D_HID, D_OUT);
    gate_kernel<<<N_TOK / G_TOK, 256, 0, stream>>>(x, Wg, bg, gate_out, cnt, lists, meta_e, meta_w);
    init_out_kernel<<<N_TOK, 256, 0, stream>>>(meta_e, meta_w, b2, out);
    expert_kernel<<<dim3(N_TOK / 16, N_EXP), 256, 0, stream>>>(x, W1T, W2T, b1, cnt, lists, meta_w, out);
}

// Round 3
// 392.270 us; speedup vs baseline: 2.0487x; 1.1783x over previous
//
#include <hip/hip_runtime.h>
#include <hip/hip_bf16.h>

#define N_TOK 16384
#define D_IN 1024
#define D_HID 256
#define D_OUT 1024
#define N_EXP 8
#define CNT_STRIDE 16   // pad expert counters to separate 64B cache lines

typedef float f32x4 __attribute__((ext_vector_type(4)));
typedef short s16x8 __attribute__((ext_vector_type(8)));
typedef short s16x4 __attribute__((ext_vector_type(4)));

__device__ __forceinline__ short f2bf(float f) {
    unsigned u = __builtin_bit_cast(unsigned, f);
    u += 0x7FFF + ((u >> 16) & 1);   // round-to-nearest-even
    return (short)(u >> 16);
}

// ---------------- zero counts ----------------
__global__ void zero_kernel(int* cnt) {
    if (threadIdx.x < N_EXP * CNT_STRIDE) cnt[threadIdx.x] = 0;
}

// ---------------- repack weights into MFMA-fragment-contiguous layout ----------------
// src W [E][K][N] (k-major, as given). For n-tile nt, k-step kk (K=32 per step):
// WF[e][(nt*(K/32) + kk)*512 + lane*8 + j] = bf16(W[e][kk*32 + (lane>>4)*8 + j][nt*16 + (lane&15)])
// so one b-frag (1 KB) is contiguous and loads as global_load_dwordx4 at base+lane*16.
__global__ __launch_bounds__(256) void repack_kernel(
    const float* __restrict__ W, short* __restrict__ WF, int K, int N)
{
    int e = blockIdx.y;
    int nt = blockIdx.x;
    int nkk = K >> 5;
    const float* we = W + (size_t)e * K * N;
    short* wfe = WF + (size_t)e * (N >> 4) * nkk * 512;
    int kl = threadIdx.x >> 6;      // 0..3: kk within group of 4
    int lane = threadIdx.x & 63;
    int q = lane >> 4, m = lane & 15;
    for (int k0 = 0; k0 < nkk; k0 += 4) {
        int kk = k0 + kl;
        s16x8 pk;
        #pragma unroll
        for (int j = 0; j < 8; ++j)
            pk[j] = f2bf(we[(size_t)(kk * 32 + q * 8 + j) * N + nt * 16 + m]);
        *(s16x8*)&wfe[((size_t)nt * nkk + kk) * 512 + lane * 8] = pk;
    }
}

// ---------------- gating: logits (fp32 exact), top-2, softmax, hierarchical dispatch ----------------
#define G_TOK 32                 // tokens per block (4 waves x 8 tokens)
__global__ __launch_bounds__(256) void gate_kernel(
    const float* __restrict__ x, const float* __restrict__ Wg,
    const float* __restrict__ bg, float* __restrict__ gate_out,
    int* __restrict__ cnt, int* __restrict__ lists,
    int* __restrict__ meta_e, float* __restrict__ meta_w)
{
    __shared__ float wgs[D_IN * 12];
    __shared__ int lcnt[N_EXP];
    __shared__ int sbase[N_EXP];
    __shared__ int ent_e[2 * G_TOK];
    __shared__ int ent_r[2 * G_TOK];

    int tid = threadIdx.x;
    #pragma unroll
    for (int i = 0; i < 8; ++i) {
        int flat = i * 256 + tid;          // float4 index 0..2047
        int d = flat >> 1, j = (flat & 1) * 4;
        float4 v = *(const float4*)&Wg[d * 8 + j];
        *(float4*)&wgs[d * 12 + j] = v;
    }
    if (tid < N_EXP) lcnt[tid] = 0;
    __syncthreads();

    int lane = tid & 63, wv = tid >> 6;
    int tbase = blockIdx.x * G_TOK;

    for (int i = 0; i < G_TOK / 4; ++i) {
        int lt = wv * (G_TOK / 4) + i;
        int t = tbase + lt;
        const float* xr = x + (size_t)t * D_IN;
        float acc[8] = {0.f, 0.f, 0.f, 0.f, 0.f, 0.f, 0.f, 0.f};
        #pragma unroll
        for (int it = 0; it < 16; ++it) {
            int d = it * 64 + lane;
            float xv = xr[d];
            float4 wa = *(const float4*)&wgs[d * 12 + 0];
            float4 wb = *(const float4*)&wgs[d * 12 + 4];
            acc[0] += xv * wa.x; acc[1] += xv * wa.y;
            acc[2] += xv * wa.z; acc[3] += xv * wa.w;
            acc[4] += xv * wb.x; acc[5] += xv * wb.y;
            acc[6] += xv * wb.z; acc[7] += xv * wb.w;
        }
        #pragma unroll
        for (int e = 0; e < 8; ++e) {
            #pragma unroll
            for (int off = 32; off >= 1; off >>= 1)
                acc[e] += __shfl_xor(acc[e], off);
        }
        if (lane == 0) {
            float lg[8];
            #pragma unroll
            for (int e = 0; e < 8; ++e) {
                lg[e] = acc[e] + bg[e];
                gate_out[(size_t)t * 8 + e] = lg[e];
            }
            int i0 = 0;
            #pragma unroll
            for (int e = 1; e < 8; ++e) if (lg[e] > lg[i0]) i0 = e;   // ties -> lowest idx
            int i1 = -1;
            #pragma unroll
            for (int e = 0; e < 8; ++e)
                if (e != i0 && (i1 < 0 || lg[e] > lg[i1])) i1 = e;
            float ex = expf(lg[i1] - lg[i0]);
            float inv = 1.f / (1.f + ex);
            meta_e[2 * t] = i0; meta_e[2 * t + 1] = i1;
            meta_w[2 * t] = inv; meta_w[2 * t + 1] = ex * inv;
            int r0 = atomicAdd(&lcnt[i0], 1);
            int r1 = atomicAdd(&lcnt[i1], 1);
            ent_e[2 * lt] = i0;     ent_r[2 * lt] = r0;
            ent_e[2 * lt + 1] = i1; ent_r[2 * lt + 1] = r1;
        }
    }
    __syncthreads();
    if (tid < N_EXP) sbase[tid] = atomicAdd(&cnt[tid * CNT_STRIDE], lcnt[tid]);
    __syncthreads();
    if (tid < 2 * G_TOK) {
        int e = ent_e[tid];
        lists[e * N_TOK + sbase[e] + ent_r[tid]] = tbase * 2 + tid;  // code = t*2 + slot
    }
}

// ---------------- out pre-init with combined bias: out[t] = w0*b2[e0] + w1*b2[e1] ----------------
__global__ __launch_bounds__(256) void init_out_kernel(
    const int* __restrict__ meta_e, const float* __restrict__ meta_w,
    const float* __restrict__ b2, float* __restrict__ out)
{
    int t = blockIdx.x;
    int e0 = meta_e[2 * t], e1 = meta_e[2 * t + 1];
    float w0 = meta_w[2 * t], w1 = meta_w[2 * t + 1];
    int c = threadIdx.x * 4;
    float4 a = *(const float4*)&b2[(size_t)e0 * D_OUT + c];
    float4 b = *(const float4*)&b2[(size_t)e1 * D_OUT + c];
    float4 r;
    r.x = w0 * a.x + w1 * b.x;
    r.y = w0 * a.y + w1 * b.y;
    r.z = w0 * a.z + w1 * b.z;
    r.w = w0 * a.w + w1 * b.w;
    *(float4*)&out[(size_t)t * D_OUT + c] = r;
}

// ---------------- expert MLP: 64-token tile, register-blocked bf16 MFMA ----------------
// 512 threads = 8 waves. Each wave: 4 m-tiles x 2 n-tiles per pass -> one B-frag
// feeds 4 MFMAs (4x less weight traffic than M=16). B-frags contiguous via repack.
#define BM 64
#define BK 512
#define XLD 520   // 512+8: row stride 1040 B = 260 dwords == 4 mod 32 -> conflict-free b128
#define HLD 264   // 256+8: same property

__global__ __launch_bounds__(512, 4) void expert_kernel(
    const float* __restrict__ x,
    const short* __restrict__ W1F, const short* __restrict__ W2F,
    const float* __restrict__ b1,
    const int* __restrict__ cnt, const int* __restrict__ lists,
    const float* __restrict__ meta_w,
    float* __restrict__ out)
{
    int e = blockIdx.y;
    int me = cnt[e * CNT_STRIDE];
    int base = blockIdx.x * BM;
    if (base >= me) return;

    __shared__ short smem[BM * XLD];   // xs during GEMM1; aliased as hs for GEMM2
    short* xs = smem;
    short* hs = smem;
    __shared__ int toks[BM];
    __shared__ float wts[BM];

    int tid = threadIdx.x;
    if (tid < BM) {
        int gi = base + tid;
        if (gi < me) {
            int enc = lists[e * N_TOK + gi];
            toks[tid] = enc >> 1;
            wts[tid] = meta_w[enc];
        } else { toks[tid] = 0; wts[tid] = 0.f; }
    }
    __syncthreads();

    int lane = tid & 63, wv = tid >> 6;
    int m = lane & 15, q = lane >> 4;

    const short* w1e = W1F + (size_t)e * (16 * 32 * 512);
    const short* w2e = W2F + (size_t)e * (64 * 8 * 512);

    // ---- GEMM1: H[64x256] = relu(X @ W1 + b1), K=1024 in 2 chunks of 512 ----
    f32x4 acc1[4][2];
    #pragma unroll
    for (int mt = 0; mt < 4; ++mt)
        #pragma unroll
        for (int ntl = 0; ntl < 2; ++ntl)
            acc1[mt][ntl] = (f32x4){0.f, 0.f, 0.f, 0.f};

    for (int ck = 0; ck < 2; ++ck) {
        if (ck) __syncthreads();
        // stage 64 x 512 f32 -> bf16 LDS (wave-uniform row per pass -> scalar toks load)
        #pragma unroll
        for (int p = 0; p < 16; ++p) {
            int flat = p * 512 + tid;
            int row = flat >> 7;            // 128 float4 per row
            int c4 = flat & 127;
            const float4 v = *(const float4*)&x[(size_t)toks[row] * D_IN + ck * BK + c4 * 4];
            s16x4 pk; pk[0] = f2bf(v.x); pk[1] = f2bf(v.y); pk[2] = f2bf(v.z); pk[3] = f2bf(v.w);
            *(s16x4*)&xs[row * XLD + c4 * 4] = pk;
        }
        __syncthreads();
        #pragma unroll
        for (int kk = 0; kk < 16; ++kk) {
            int kg = ck * 16 + kk;
            s16x8 a[4];
            #pragma unroll
            for (int mt = 0; mt < 4; ++mt)
                a[mt] = *(const s16x8*)&xs[(mt * 16 + m) * XLD + kk * 32 + q * 8];
            #pragma unroll
            for (int ntl = 0; ntl < 2; ++ntl) {
                int nt = wv * 2 + ntl;
                s16x8 b = *(const s16x8*)&w1e[((size_t)(nt * 32 + kg)) * 512 + lane * 8];
                #pragma unroll
                for (int mt = 0; mt < 4; ++mt)
                    acc1[mt][ntl] = __builtin_amdgcn_mfma_f32_16x16x32_bf16(a[mt], b, acc1[mt][ntl], 0, 0, 0);
            }
        }
    }

    // ---- epilogue 1: bias + relu -> hs (aliases xs; barrier-protected) ----
    __syncthreads();
    const float* b1e = b1 + (size_t)e * D_HID;
    #pragma unroll
    for (int ntl = 0; ntl < 2; ++ntl) {
        int j = wv * 32 + ntl * 16 + m;       // C/D: col = lane&15
        float bias = b1e[j];
        #pragma unroll
        for (int mt = 0; mt < 4; ++mt) {
            #pragma unroll
            for (int r = 0; r < 4; ++r) {
                int row = mt * 16 + q * 4 + r;  // C/D: row = (lane>>4)*4 + reg
                float h = acc1[mt][ntl][r] + bias;
                h = h > 0.f ? h : 0.f;
                hs[row * HLD + j] = f2bf(h);
            }
        }
    }
    __syncthreads();

    // ---- GEMM2: Y[64x1024] = H @ W2, K=256; 4 passes of 32 cols per wave ----
    for (int pass = 0; pass < 4; ++pass) {
        f32x4 acc2[4][2];
        #pragma unroll
        for (int mt = 0; mt < 4; ++mt)
            #pragma unroll
            for (int ntl = 0; ntl < 2; ++ntl)
                acc2[mt][ntl] = (f32x4){0.f, 0.f, 0.f, 0.f};
        #pragma unroll
        for (int kk = 0; kk < 8; ++kk) {
            s16x8 a[4];
            #pragma unroll
            for (int mt = 0; mt < 4; ++mt)
                a[mt] = *(const s16x8*)&hs[(mt * 16 + m) * HLD + kk * 32 + q * 8];
            #pragma unroll
            for (int ntl = 0; ntl < 2; ++ntl) {
                int nt = wv * 8 + pass * 2 + ntl;
                s16x8 b = *(const s16x8*)&w2e[((size_t)(nt * 8 + kk)) * 512 + lane * 8];
                #pragma unroll
                for (int mt = 0; mt < 4; ++mt)
                    acc2[mt][ntl] = __builtin_amdgcn_mfma_f32_16x16x32_bf16(a[mt], b, acc2[mt][ntl], 0, 0, 0);
            }
        }
        // ---- epilogue 2: weighted atomic scatter-add ----
        #pragma unroll
        for (int ntl = 0; ntl < 2; ++ntl) {
            int col = (wv * 8 + pass * 2 + ntl) * 16 + m;
            #pragma unroll
            for (int mt = 0; mt < 4; ++mt) {
                #pragma unroll
                for (int r = 0; r < 4; ++r) {
                    int row = mt * 16 + q * 4 + r;
                    if (base + row < me)
                        unsafeAtomicAdd(&out[(size_t)toks[row] * D_OUT + col],
                                        wts[row] * acc2[mt][ntl][r]);
                }
            }
        }
    }
}

extern "C" void kernel_launch(void* const* d_in, const int* in_sizes, int n_in,
                              void* d_out, int out_size, void* d_ws, size_t ws_size,
                              hipStream_t stream) {
    const float* x  = (const float*)d_in[0];
    const float* Wg = (const float*)d_in[1];
    const float* bg = (const float*)d_in[2];
    const float* W1 = (const float*)d_in[3];
    const float* b1 = (const float*)d_in[4];
    const float* W2 = (const float*)d_in[5];
    const float* b2 = (const float*)d_in[6];

    float* out = (float*)d_out;                         // [16384,1024]
    float* gate_out = out + (size_t)N_TOK * D_OUT;      // [16384,8]

    // workspace layout (~8.9 MB)
    short* W1F   = (short*)d_ws;                        // [8][16*32*512] bf16 frag-major
    short* W2F   = W1F + (size_t)N_EXP * 16 * 32 * 512; // [8][64*8*512]
    int*   cnt   = (int*)(W2F + (size_t)N_EXP * 64 * 8 * 512);  // [8*16] padded
    int*   lists = cnt + N_EXP * CNT_STRIDE;            // [8][16384]
    int*   meta_e = lists + N_EXP * N_TOK;              // [16384][2]
    float* meta_w = (float*)(meta_e + 2 * N_TOK);       // [16384][2]

    zero_kernel<<<1, 128, 0, stream>>>(cnt);
    repack_kernel<<<dim3(D_HID / 16, N_EXP), 256, 0, stream>>>(W1, W1F, D_IN, D_HID);
    repack_kernel<<<dim3(D_OUT / 16, N_EXP), 256, 0, stream>>>(W2, W2F, D_HID, D_OUT);
    gate_kernel<<<N_TOK / G_TOK, 256, 0, stream>>>(x, Wg, bg, gate_out, cnt, lists, meta_e, meta_w);
    init_out_kernel<<<N_TOK, 256, 0, stream>>>(meta_e, meta_w, b2, out);
    expert_kernel<<<dim3(N_TOK / BM, N_EXP), 512, 0, stream>>>(x, W1F, W2F, b1, cnt, lists, meta_w, out);
}

// Round 5
// 382.229 us; speedup vs baseline: 2.1025x; 1.0263x over previous
//
#include <hip/hip_runtime.h>
#include <hip/hip_bf16.h>

#define N_TOK 16384
#define D_IN 1024
#define D_HID 256
#define D_OUT 1024
#define N_EXP 8
#define CNT_STRIDE 16   // pad expert counters to separate 64B cache lines

typedef float f32x4 __attribute__((ext_vector_type(4)));
typedef short s16x8 __attribute__((ext_vector_type(8)));
typedef short s16x4 __attribute__((ext_vector_type(4)));

__device__ __forceinline__ short f2bf(float f) {
    unsigned u = __builtin_bit_cast(unsigned, f);
    u += 0x7FFF + ((u >> 16) & 1);   // round-to-nearest-even
    return (short)(u >> 16);
}

// ---------------- zero counts ----------------
__global__ void zero_kernel(int* cnt) {
    if (threadIdx.x < N_EXP * CNT_STRIDE) cnt[threadIdx.x] = 0;
}

// ---------------- repack weights into MFMA-fragment-contiguous layout ----------------
// src W [E][K][N] (k-major, as given). For n-tile nt, k-step kk (K=32 per step):
// WF[e][(nt*(K/32) + kk)*512 + lane*8 + j] = bf16(W[e][kk*32 + (lane>>4)*8 + j][nt*16 + (lane&15)])
// so one b-frag (1 KB) is contiguous and loads as global_load_dwordx4 at base+lane*16.
__global__ __launch_bounds__(256) void repack_kernel(
    const float* __restrict__ W, short* __restrict__ WF, int K, int N)
{
    int e = blockIdx.y;
    int nt = blockIdx.x;
    int nkk = K >> 5;
    const float* we = W + (size_t)e * K * N;
    short* wfe = WF + (size_t)e * (N >> 4) * nkk * 512;
    int kl = threadIdx.x >> 6;      // 0..3: kk within group of 4
    int lane = threadIdx.x & 63;
    int q = lane >> 4, m = lane & 15;
    for (int k0 = 0; k0 < nkk; k0 += 4) {
        int kk = k0 + kl;
        s16x8 pk;
        #pragma unroll
        for (int j = 0; j < 8; ++j)
            pk[j] = f2bf(we[(size_t)(kk * 32 + q * 8 + j) * N + nt * 16 + m]);
        *(s16x8*)&wfe[((size_t)nt * nkk + kk) * 512 + lane * 8] = pk;
    }
}

// ---------------- gating: logits (fp32 exact), top-2, softmax, hierarchical dispatch ----------------
#define G_TOK 32                 // tokens per block (4 waves x 8 tokens)
__global__ __launch_bounds__(256) void gate_kernel(
    const float* __restrict__ x, const float* __restrict__ Wg,
    const float* __restrict__ bg, float* __restrict__ gate_out,
    int* __restrict__ cnt, int* __restrict__ lists,
    int* __restrict__ meta_e, float* __restrict__ meta_w)
{
    __shared__ float wgs[D_IN * 12];
    __shared__ int lcnt[N_EXP];
    __shared__ int sbase[N_EXP];
    __shared__ int ent_e[2 * G_TOK];
    __shared__ int ent_r[2 * G_TOK];

    int tid = threadIdx.x;
    #pragma unroll
    for (int i = 0; i < 8; ++i) {
        int flat = i * 256 + tid;          // float4 index 0..2047
        int d = flat >> 1, j = (flat & 1) * 4;
        float4 v = *(const float4*)&Wg[d * 8 + j];
        *(float4*)&wgs[d * 12 + j] = v;
    }
    if (tid < N_EXP) lcnt[tid] = 0;
    __syncthreads();

    int lane = tid & 63, wv = tid >> 6;
    int tbase = blockIdx.x * G_TOK;

    for (int i = 0; i < G_TOK / 4; ++i) {
        int lt = wv * (G_TOK / 4) + i;
        int t = tbase + lt;
        const float* xr = x + (size_t)t * D_IN;
        float acc[8] = {0.f, 0.f, 0.f, 0.f, 0.f, 0.f, 0.f, 0.f};
        #pragma unroll
        for (int it = 0; it < 16; ++it) {
            int d = it * 64 + lane;
            float xv = xr[d];
            float4 wa = *(const float4*)&wgs[d * 12 + 0];
            float4 wb = *(const float4*)&wgs[d * 12 + 4];
            acc[0] += xv * wa.x; acc[1] += xv * wa.y;
            acc[2] += xv * wa.z; acc[3] += xv * wa.w;
            acc[4] += xv * wb.x; acc[5] += xv * wb.y;
            acc[6] += xv * wb.z; acc[7] += xv * wb.w;
        }
        #pragma unroll
        for (int e = 0; e < 8; ++e) {
            #pragma unroll
            for (int off = 32; off >= 1; off >>= 1)
                acc[e] += __shfl_xor(acc[e], off);
        }
        if (lane == 0) {
            float lg[8];
            #pragma unroll
            for (int e = 0; e < 8; ++e) {
                lg[e] = acc[e] + bg[e];
                gate_out[(size_t)t * 8 + e] = lg[e];
            }
            int i0 = 0;
            #pragma unroll
            for (int e = 1; e < 8; ++e) if (lg[e] > lg[i0]) i0 = e;   // ties -> lowest idx
            int i1 = -1;
            #pragma unroll
            for (int e = 0; e < 8; ++e)
                if (e != i0 && (i1 < 0 || lg[e] > lg[i1])) i1 = e;
            float ex = expf(lg[i1] - lg[i0]);
            float inv = 1.f / (1.f + ex);
            meta_e[2 * t] = i0; meta_e[2 * t + 1] = i1;
            meta_w[2 * t] = inv; meta_w[2 * t + 1] = ex * inv;
            int r0 = atomicAdd(&lcnt[i0], 1);
            int r1 = atomicAdd(&lcnt[i1], 1);
            ent_e[2 * lt] = i0;     ent_r[2 * lt] = r0;
            ent_e[2 * lt + 1] = i1; ent_r[2 * lt + 1] = r1;
        }
    }
    __syncthreads();
    if (tid < N_EXP) sbase[tid] = atomicAdd(&cnt[tid * CNT_STRIDE], lcnt[tid]);
    __syncthreads();
    if (tid < 2 * G_TOK) {
        int e = ent_e[tid];
        lists[e * N_TOK + sbase[e] + ent_r[tid]] = tbase * 2 + tid;  // code = t*2 + slot
    }
}

// ---------------- out pre-init with combined bias: out[t] = w0*b2[e0] + w1*b2[e1] ----------------
__global__ __launch_bounds__(256) void init_out_kernel(
    const int* __restrict__ meta_e, const float* __restrict__ meta_w,
    const float* __restrict__ b2, float* __restrict__ out)
{
    int t = blockIdx.x;
    int e0 = meta_e[2 * t], e1 = meta_e[2 * t + 1];
    float w0 = meta_w[2 * t], w1 = meta_w[2 * t + 1];
    int c = threadIdx.x * 4;
    float4 a = *(const float4*)&b2[(size_t)e0 * D_OUT + c];
    float4 b = *(const float4*)&b2[(size_t)e1 * D_OUT + c];
    float4 r;
    r.x = w0 * a.x + w1 * b.x;
    r.y = w0 * a.y + w1 * b.y;
    r.z = w0 * a.z + w1 * b.z;
    r.w = w0 * a.w + w1 * b.w;
    *(float4*)&out[(size_t)t * D_OUT + c] = r;
}

// ---------------- expert MLP: 64-token tile, register-blocked bf16 MFMA ----------------
// 512 threads = 8 waves. Each wave: 4 m-tiles x 2 n-tiles per pass -> one B-frag
// feeds 4 MFMAs. B-frags contiguous via repack.
// 1D grid of 2048 blocks, decode e = id & 7, mb = id >> 3: the ~512 WORKING
// blocks (mb < me/64) get CONTIGUOUS linear ids -> spread across all 256 CUs.
// The R3 (m-major, expert-minor) grid put all workers on CU slots 0-7 of each
// XCD (exactly the measured 25% occupancy ceiling).
#define BM 64
#define BK 512
#define XLD 520   // 512+8: row stride 1040 B = 260 dwords == 4 mod 32 -> conflict-free b128
#define HLD 264   // 256+8: same property

__global__ __launch_bounds__(512, 4) void expert_kernel(
    const float* __restrict__ x,
    const short* __restrict__ W1F, const short* __restrict__ W2F,
    const float* __restrict__ b1,
    const int* __restrict__ cnt, const int* __restrict__ lists,
    const float* __restrict__ meta_w,
    float* __restrict__ out)
{
    int e = blockIdx.x & (N_EXP - 1);
    int me = cnt[e * CNT_STRIDE];
    int base = (blockIdx.x >> 3) * BM;
    if (base >= me) return;

    __shared__ short smem[BM * XLD];   // xs during GEMM1; aliased as hs for GEMM2
    short* xs = smem;
    short* hs = smem;
    __shared__ int toks[BM];
    __shared__ float wts[BM];

    int tid = threadIdx.x;
    if (tid < BM) {
        int gi = base + tid;
        if (gi < me) {
            int enc = lists[e * N_TOK + gi];
            toks[tid] = enc >> 1;
            wts[tid] = meta_w[enc];
        } else { toks[tid] = 0; wts[tid] = 0.f; }
    }
    __syncthreads();

    int lane = tid & 63, wv = tid >> 6;
    int m = lane & 15, q = lane >> 4;

    const short* w1e = W1F + (size_t)e * (16 * 32 * 512);
    const short* w2e = W2F + (size_t)e * (64 * 8 * 512);

    // ---- GEMM1: H[64x256] = relu(X @ W1 + b1), K=1024 in 2 chunks of 512 ----
    f32x4 acc1[4][2];
    #pragma unroll
    for (int mt = 0; mt < 4; ++mt)
        #pragma unroll
        for (int ntl = 0; ntl < 2; ++ntl)
            acc1[mt][ntl] = (f32x4){0.f, 0.f, 0.f, 0.f};

    for (int ck = 0; ck < 2; ++ck) {
        if (ck) __syncthreads();
        // stage 64 x 512 f32 -> bf16 LDS
        #pragma unroll
        for (int p = 0; p < 16; ++p) {
            int flat = p * 512 + tid;
            int row = flat >> 7;            // 128 float4 per row
            int c4 = flat & 127;
            const float4 v = *(const float4*)&x[(size_t)toks[row] * D_IN + ck * BK + c4 * 4];
            s16x4 pk; pk[0] = f2bf(v.x); pk[1] = f2bf(v.y); pk[2] = f2bf(v.z); pk[3] = f2bf(v.w);
            *(s16x4*)&xs[row * XLD + c4 * 4] = pk;
        }
        __syncthreads();
        #pragma unroll
        for (int kk = 0; kk < 16; ++kk) {
            int kg = ck * 16 + kk;
            s16x8 a[4];
            #pragma unroll
            for (int mt = 0; mt < 4; ++mt)
                a[mt] = *(const s16x8*)&xs[(mt * 16 + m) * XLD + kk * 32 + q * 8];
            #pragma unroll
            for (int ntl = 0; ntl < 2; ++ntl) {
                int nt = wv * 2 + ntl;
                s16x8 b = *(const s16x8*)&w1e[((size_t)(nt * 32 + kg)) * 512 + lane * 8];
                #pragma unroll
                for (int mt = 0; mt < 4; ++mt)
                    acc1[mt][ntl] = __builtin_amdgcn_mfma_f32_16x16x32_bf16(a[mt], b, acc1[mt][ntl], 0, 0, 0);
            }
        }
    }

    // ---- epilogue 1: bias + relu -> hs (aliases xs; barrier-protected) ----
    __syncthreads();
    const float* b1e = b1 + (size_t)e * D_HID;
    #pragma unroll
    for (int ntl = 0; ntl < 2; ++ntl) {
        int j = wv * 32 + ntl * 16 + m;       // C/D: col = lane&15
        float bias = b1e[j];
        #pragma unroll
        for (int mt = 0; mt < 4; ++mt) {
            #pragma unroll
            for (int r = 0; r < 4; ++r) {
                int row = mt * 16 + q * 4 + r;  // C/D: row = (lane>>4)*4 + reg
                float h = acc1[mt][ntl][r] + bias;
                h = h > 0.f ? h : 0.f;
                hs[row * HLD + j] = f2bf(h);
            }
        }
    }
    __syncthreads();

    // ---- GEMM2: Y[64x1024] = H @ W2, K=256; 4 passes of 32 cols per wave ----
    for (int pass = 0; pass < 4; ++pass) {
        f32x4 acc2[4][2];
        #pragma unroll
        for (int mt = 0; mt < 4; ++mt)
            #pragma unroll
            for (int ntl = 0; ntl < 2; ++ntl)
                acc2[mt][ntl] = (f32x4){0.f, 0.f, 0.f, 0.f};
        #pragma unroll
        for (int kk = 0; kk < 8; ++kk) {
            s16x8 a[4];
            #pragma unroll
            for (int mt = 0; mt < 4; ++mt)
                a[mt] = *(const s16x8*)&hs[(mt * 16 + m) * HLD + kk * 32 + q * 8];
            #pragma unroll
            for (int ntl = 0; ntl < 2; ++ntl) {
                int nt = wv * 8 + pass * 2 + ntl;
                s16x8 b = *(const s16x8*)&w2e[((size_t)(nt * 8 + kk)) * 512 + lane * 8];
                #pragma unroll
                for (int mt = 0; mt < 4; ++mt)
                    acc2[mt][ntl] = __builtin_amdgcn_mfma_f32_16x16x32_bf16(a[mt], b, acc2[mt][ntl], 0, 0, 0);
            }
        }
        // ---- epilogue 2: weighted atomic scatter-add ----
        #pragma unroll
        for (int ntl = 0; ntl < 2; ++ntl) {
            int col = (wv * 8 + pass * 2 + ntl) * 16 + m;
            #pragma unroll
            for (int mt = 0; mt < 4; ++mt) {
                #pragma unroll
                for (int r = 0; r < 4; ++r) {
                    int row = mt * 16 + q * 4 + r;
                    if (base + row < me)
                        unsafeAtomicAdd(&out[(size_t)toks[row] * D_OUT + col],
                                        wts[row] * acc2[mt][ntl][r]);
                }
            }
        }
    }
}

extern "C" void kernel_launch(void* const* d_in, const int* in_sizes, int n_in,
                              void* d_out, int out_size, void* d_ws, size_t ws_size,
                              hipStream_t stream) {
    const float* x  = (const float*)d_in[0];
    const float* Wg = (const float*)d_in[1];
    const float* bg = (const float*)d_in[2];
    const float* W1 = (const float*)d_in[3];
    const float* b1 = (const float*)d_in[4];
    const float* W2 = (const float*)d_in[5];
    const float* b2 = (const float*)d_in[6];

    float* out = (float*)d_out;                         // [16384,1024]
    float* gate_out = out + (size_t)N_TOK * D_OUT;      // [16384,8]

    // workspace layout (~8.9 MB)
    short* W1F   = (short*)d_ws;                        // [8][16*32*512] bf16 frag-major
    short* W2F   = W1F + (size_t)N_EXP * 16 * 32 * 512; // [8][64*8*512]
    int*   cnt   = (int*)(W2F + (size_t)N_EXP * 64 * 8 * 512);  // [8*16] padded
    int*   lists = cnt + N_EXP * CNT_STRIDE;            // [8][16384]
    int*   meta_e = lists + N_EXP * N_TOK;              // [16384][2]
    float* meta_w = (float*)(meta_e + 2 * N_TOK);       // [16384][2]

    zero_kernel<<<1, 128, 0, stream>>>(cnt);
    repack_kernel<<<dim3(D_HID / 16, N_EXP), 256, 0, stream>>>(W1, W1F, D_IN, D_HID);
    repack_kernel<<<dim3(D_OUT / 16, N_EXP), 256, 0, stream>>>(W2, W2F, D_HID, D_OUT);
    gate_kernel<<<N_TOK / G_TOK, 256, 0, stream>>>(x, Wg, bg, gate_out, cnt, lists, meta_e, meta_w);
    init_out_kernel<<<N_TOK, 256, 0, stream>>>(meta_e, meta_w, b2, out);
    expert_kernel<<<(N_TOK / BM) * N_EXP, 512, 0, stream>>>(x, W1F, W2F, b1, cnt, lists, meta_w, out);
}